// Round 2
// baseline (98.384 us; speedup 1.0000x reference)
//
#include <hip/hip_runtime.h>
#include <math.h>

#define G_N   2048
#define NT    32
#define NP    32
#define NR    64
#define NRAY  (NT * NP)

// ---------------------------------------------------------------------------
// Kernel 1: per-gaussian precompute.
// Folds -0.5*log2(e) into the precision matrix and log2(opacity) into C so the
// hot loop is exp2(fma(fma(A,t,B),t,C)).
// Layout per g (12 floats, 48B = 3 aligned float4):
//   [0..5]  c*P  : p00 p11 p22 p01 p02 p12
//   [6..8]  2c*(P om)
//   [9]     c*(om^T P om) + log2(opac)
//   [10]    albedo
//   [11]    pad
// ---------------------------------------------------------------------------
__global__ __launch_bounds__(256) void k_pre(
    const float* __restrict__ means, const float* __restrict__ scales,
    const float* __restrict__ rots, const float* __restrict__ opacs,
    const float* __restrict__ feats, const float* __restrict__ cam,
    float* __restrict__ ws) {
  int g = blockIdx.x * 256 + threadIdx.x;
  if (g >= G_N) return;

  float mx = means[3*g+0], my = means[3*g+1], mz = means[3*g+2];
  // inv_s2 = 1/(exp(s)^2) = exp(-2s)
  float i0 = expf(-2.0f * scales[3*g+0]);
  float i1 = expf(-2.0f * scales[3*g+1]);
  float i2 = expf(-2.0f * scales[3*g+2]);

  float qw = rots[4*g+0], qx = rots[4*g+1], qy = rots[4*g+2], qz = rots[4*g+3];
  float inv = 1.0f / (sqrtf(qw*qw + qx*qx + qy*qy + qz*qz) + 1e-12f);
  qw *= inv; qx *= inv; qy *= inv; qz *= inv;

  float R00 = 1.f - 2.f*(qy*qy + qz*qz), R01 = 2.f*(qx*qy - qw*qz), R02 = 2.f*(qx*qz + qw*qy);
  float R10 = 2.f*(qx*qy + qw*qz), R11 = 1.f - 2.f*(qx*qx + qz*qz), R12 = 2.f*(qy*qz - qw*qx);
  float R20 = 2.f*(qx*qz - qw*qy), R21 = 2.f*(qy*qz + qw*qx), R22 = 1.f - 2.f*(qx*qx + qy*qy);

  // P = R diag(inv_s2) R^T
  float p00 = R00*R00*i0 + R01*R01*i1 + R02*R02*i2;
  float p11 = R10*R10*i0 + R11*R11*i1 + R12*R12*i2;
  float p22 = R20*R20*i0 + R21*R21*i1 + R22*R22*i2;
  float p01 = R00*R10*i0 + R01*R11*i1 + R02*R12*i2;
  float p02 = R00*R20*i0 + R01*R21*i1 + R02*R22*i2;
  float p12 = R10*R20*i0 + R11*R21*i1 + R12*R22*i2;

  float ox = cam[0] - mx, oy = cam[1] - my, oz = cam[2] - mz;
  float Px = p00*ox + p01*oy + p02*oz;
  float Py = p01*ox + p11*oy + p12*oz;
  float Pz = p02*ox + p12*oy + p22*oz;
  float Cq = ox*Px + oy*Py + oz*Pz;

  float op = 1.0f / (1.0f + expf(-opacs[g]));

  const float SH_C0 = 0.28209479177387814f;
  float a0 = fmaxf(SH_C0*feats[3*g+0] + 0.5f, 0.f);
  float a1 = fmaxf(SH_C0*feats[3*g+1] + 0.5f, 0.f);
  float a2 = fmaxf(SH_C0*feats[3*g+2] + 0.5f, 0.f);
  float alb = (a0 + a1 + a2) * (1.0f/3.0f);

  const float c = -0.7213475204444817f;  // -0.5 * log2(e)
  float* o = ws + 12*g;
  o[0] = c*p00; o[1] = c*p11; o[2] = c*p22;
  o[3] = c*p01; o[4] = c*p02; o[5] = c*p12;
  o[6] = 2.f*c*Px; o[7] = 2.f*c*Py; o[8] = 2.f*c*Pz;
  o[9] = c*Cq + log2f(op);
  o[10] = alb; o[11] = 0.f;
}

// ---------------------------------------------------------------------------
// Kernel 2: main render. One block per ray; 256 threads = 4 waves.
// Phase 1: all threads cooperatively fold ray dir into per-g (A,B,C,albedo) in LDS.
// Phase 2: lane = t index (64 t == one wave), each wave sums a quarter of g.
// Phase 3: LDS reduce across waves; wave 0 does the t-cumsum as a shuffle scan.
// ---------------------------------------------------------------------------
__global__ __launch_bounds__(256) void k_main(const float* __restrict__ ws,
                                              float* __restrict__ out) {
  __shared__ float4 abce[G_N];       // 32 KB
  __shared__ float red[2][4][64];    // 2 KB

  const int ray = blockIdx.x;        // ray = ti*NP + pj
  const int ti = ray >> 5;
  const int pj = ray & 31;
  const float th = (float)ti * (float)(M_PI / 2.0 / (NT - 1));
  const float ph = (float)(-M_PI / 2.0) + (float)pj * (float)(M_PI / (NP - 1));
  float sth, cth, sph, cph;
  sincosf(th, &sth, &cth);
  sincosf(ph, &sph, &cph);
  const float dx = sth * cph, dy = sth * sph, dz = cth;
  const float dxx = dx*dx, dyy = dy*dy, dzz = dz*dz;
  const float dxy = 2.f*dx*dy, dxz = 2.f*dx*dz, dyz = 2.f*dy*dz;

  const int tid = threadIdx.x;

  // Phase 1: per-(ray, g) quadratic coefficients -> LDS
  // Mapping (see k_pre): a=(cP00,cP11,cP22,cP01) b=(cP02,cP12,2cPx,2cPy)
  //                      cc=(2cPz, C, albedo, pad)
  #pragma unroll
  for (int i = 0; i < G_N / 256; ++i) {
    int g = tid + i * 256;
    const float4* w4 = (const float4*)(ws + 12 * g);
    float4 a = w4[0], b = w4[1], cc = w4[2];
    float A2 = a.x*dxx + a.y*dyy + a.z*dzz + a.w*dxy + b.x*dxz + b.y*dyz;
    float B2 = b.z*dx + b.w*dy + cc.x*dz;   // 2c*(P om)·d
    abce[g] = make_float4(A2, B2, cc.y, cc.z);  // (cA, cB, C, albedo)
  }
  __syncthreads();

  // Phase 2: each wave handles 512 gaussians; lane = t sample.
  const int lane = tid & 63;
  const int wv = tid >> 6;
  const float t = 0.5f + (float)lane * (2.0f / 63.0f);

  const float4* base = abce + wv * (G_N / 4);
  float d0 = 0.f, d1 = 0.f, d2 = 0.f, d3 = 0.f;
  float h0 = 0.f, h1 = 0.f, h2 = 0.f, h3 = 0.f;
  #pragma unroll 4
  for (int g = 0; g < G_N / 4; g += 4) {
    float4 e0 = base[g+0];
    float4 e1 = base[g+1];
    float4 e2 = base[g+2];
    float4 e3 = base[g+3];
    float x0 = __builtin_amdgcn_exp2f(fmaf(fmaf(e0.x, t, e0.y), t, e0.z));
    float x1 = __builtin_amdgcn_exp2f(fmaf(fmaf(e1.x, t, e1.y), t, e1.z));
    float x2 = __builtin_amdgcn_exp2f(fmaf(fmaf(e2.x, t, e2.y), t, e2.z));
    float x3 = __builtin_amdgcn_exp2f(fmaf(fmaf(e3.x, t, e3.y), t, e3.z));
    d0 += x0; h0 = fmaf(x0, e0.w, h0);
    d1 += x1; h1 = fmaf(x1, e1.w, h1);
    d2 += x2; h2 = fmaf(x2, e2.w, h2);
    d3 += x3; h3 = fmaf(x3, e3.w, h3);
  }
  red[0][wv][lane] = (d0 + d1) + (d2 + d3);
  red[1][wv][lane] = (h0 + h1) + (h2 + h3);
  __syncthreads();

  // Phase 3: reduce across 4 waves, then transmittance scan over t (wave 0).
  if (tid < 64) {
    float D  = (red[0][0][tid] + red[0][1][tid]) + (red[0][2][tid] + red[0][3][tid]);
    float Rh = (red[1][0][tid] + red[1][1][tid]) + (red[1][2][tid] + red[1][3][tid]);
    const float step = 1.0f * 0.03125f;  // C_LIGHT * DELTA_T
    float s = D * step;
    float inc = s;
    #pragma unroll
    for (int off = 1; off < 64; off <<= 1) {
      float v = __shfl_up(inc, off, 64);
      if (tid >= off) inc += v;
    }
    float excl = inc - s;
    float T = expf(-excl);
    float tt = 0.5f + (float)tid * (2.0f / 63.0f);
    float res = Rh * T / (tt * tt + 1e-8f) * sth;
    out[tid * NRAY + ray] = res;
  }
}

// ---------------------------------------------------------------------------
// Kernel 3: histogram. One block per t bin; sum 1024 rays.
// ---------------------------------------------------------------------------
__global__ __launch_bounds__(256) void k_hist(const float* __restrict__ res,
                                              float* __restrict__ hist) {
  const int t = blockIdx.x;
  const int tid = threadIdx.x;
  float s = 0.f;
  #pragma unroll
  for (int r = tid; r < NRAY; r += 256) s += res[t * NRAY + r];
  #pragma unroll
  for (int off = 32; off > 0; off >>= 1) s += __shfl_down(s, off, 64);
  __shared__ float sm[4];
  if ((tid & 63) == 0) sm[tid >> 6] = s;
  __syncthreads();
  if (tid == 0) {
    const float dtdp = (float)((M_PI / 2.0 / NT) * (M_PI / NP));
    hist[t] = ((sm[0] + sm[1]) + (sm[2] + sm[3])) * dtdp;
  }
}

extern "C" void kernel_launch(void* const* d_in, const int* in_sizes, int n_in,
                              void* d_out, int out_size, void* d_ws, size_t ws_size,
                              hipStream_t stream) {
  const float* means  = (const float*)d_in[0];
  const float* scales = (const float*)d_in[1];
  const float* rots   = (const float*)d_in[2];
  const float* opacs  = (const float*)d_in[3];
  const float* feats  = (const float*)d_in[4];
  const float* cam    = (const float*)d_in[5];
  // d_in[6..8] = num_theta/num_phi/num_r (fixed at 32/32/64 per setup_inputs)

  float* ws  = (float*)d_ws;
  float* out = (float*)d_out;

  k_pre <<<G_N / 256, 256, 0, stream>>>(means, scales, rots, opacs, feats, cam, ws);
  k_main<<<NRAY,      256, 0, stream>>>(ws, out);
  k_hist<<<NR,        256, 0, stream>>>(out, out + NR * NRAY);
}

// Round 4
// 97.753 us; speedup vs baseline: 1.0065x; 1.0065x over previous
//
#include <hip/hip_runtime.h>
#include <math.h>

#define G_N   2048
#define NT    32
#define NP    32
#define NR    64
#define NRAY  (NT * NP)
#define NPAIR (G_N / 2)

typedef float f32x2 __attribute__((ext_vector_type(2)));

// Packed fp32 FMA (CDNA2+ VOP3P). Component-wise: d.lo=a.lo*b.lo+c.lo, hi likewise.
__device__ __forceinline__ f32x2 pk_fma(f32x2 a, f32x2 b, f32x2 c) {
  f32x2 d;
  asm("v_pk_fma_f32 %0, %1, %2, %3" : "=v"(d) : "v"(a), "v"(b), "v"(c));
  return d;
}

// ---------------------------------------------------------------------------
// Per-gaussian coefficients for one ray, computed from raw inputs.
// Returns (c*A, c*B, c*Cq + log2(opac), albedo) where the quadratic is
// exp2(cA*t^2 + cB*t + C), c = -0.5*log2(e).
// ---------------------------------------------------------------------------
__device__ __forceinline__ float4 gauss_coef(
    int g,
    const float* __restrict__ means, const float* __restrict__ scales,
    const float* __restrict__ rots, const float* __restrict__ opacs,
    const float* __restrict__ feats, float cx, float cy, float cz,
    float dxx, float dyy, float dzz, float dxy, float dxz, float dyz,
    float dx, float dy, float dz) {
  // inv_s2 = exp(-2s) = exp2(-2*log2e * s)
  const float n2log2e = -2.8853900817779268f;
  float i0 = __builtin_amdgcn_exp2f(n2log2e * scales[3*g+0]);
  float i1 = __builtin_amdgcn_exp2f(n2log2e * scales[3*g+1]);
  float i2 = __builtin_amdgcn_exp2f(n2log2e * scales[3*g+2]);

  float qw = rots[4*g+0], qx = rots[4*g+1], qy = rots[4*g+2], qz = rots[4*g+3];
  float inv = __builtin_amdgcn_rsqf(qw*qw + qx*qx + qy*qy + qz*qz);
  qw *= inv; qx *= inv; qy *= inv; qz *= inv;

  float R00 = 1.f - 2.f*(qy*qy + qz*qz), R01 = 2.f*(qx*qy - qw*qz), R02 = 2.f*(qx*qz + qw*qy);
  float R10 = 2.f*(qx*qy + qw*qz), R11 = 1.f - 2.f*(qx*qx + qz*qz), R12 = 2.f*(qy*qz - qw*qx);
  float R20 = 2.f*(qx*qz - qw*qy), R21 = 2.f*(qy*qz + qw*qx), R22 = 1.f - 2.f*(qx*qx + qy*qy);

  // P = R diag(inv_s2) R^T
  float p00 = R00*R00*i0 + R01*R01*i1 + R02*R02*i2;
  float p11 = R10*R10*i0 + R11*R11*i1 + R12*R12*i2;
  float p22 = R20*R20*i0 + R21*R21*i1 + R22*R22*i2;
  float p01 = R00*R10*i0 + R01*R11*i1 + R02*R12*i2;
  float p02 = R00*R20*i0 + R01*R21*i1 + R02*R22*i2;
  float p12 = R10*R20*i0 + R11*R21*i1 + R12*R22*i2;

  float ox = cx - means[3*g+0], oy = cy - means[3*g+1], oz = cz - means[3*g+2];
  float Px = p00*ox + p01*oy + p02*oz;
  float Py = p01*ox + p11*oy + p12*oz;
  float Pz = p02*ox + p12*oy + p22*oz;
  float Cq = ox*Px + oy*Py + oz*Pz;

  // log2(sigmoid(x)) = -log2(1 + e^{-x})
  float u = __builtin_amdgcn_exp2f(-1.4426950408889634f * opacs[g]);
  float l2op = -__builtin_amdgcn_logf(1.0f + u);

  const float SH_C0 = 0.28209479177387814f;
  float a0 = fmaxf(SH_C0*feats[3*g+0] + 0.5f, 0.f);
  float a1 = fmaxf(SH_C0*feats[3*g+1] + 0.5f, 0.f);
  float a2 = fmaxf(SH_C0*feats[3*g+2] + 0.5f, 0.f);
  float alb = (a0 + a1 + a2) * (1.0f/3.0f);

  const float c = -0.7213475204444817f;  // -0.5 * log2(e)
  float A2 = c * (p00*dxx + p11*dyy + p22*dzz + p01*dxy + p02*dxz + p12*dyz);
  float B2 = 2.f * c * (Px*dx + Py*dy + Pz*dz);
  float Cf = c * Cq + l2op;
  return make_float4(A2, B2, Cf, alb);
}

// ---------------------------------------------------------------------------
// Main render. One block per ray; 256 threads = 4 waves.
// Phase 0: fused per-gaussian precompute + ray fold -> pair-interleaved LDS.
// Phase 1: lane = t index; each wave sums 256 gaussian-PAIRS with pk_fma.
// Phase 2: LDS reduce across waves; wave 0 does the t-scan + output.
// ---------------------------------------------------------------------------
__global__ __launch_bounds__(256, 4) void k_main(
    const float* __restrict__ means, const float* __restrict__ scales,
    const float* __restrict__ rots, const float* __restrict__ opacs,
    const float* __restrict__ feats, const float* __restrict__ cam,
    float* __restrict__ out) {
  __shared__ float4 ab[NPAIR];       // {A0,A1,B0,B1} per pair, 16 KB
  __shared__ float4 ca[NPAIR];       // {C0,C1,al0,al1} per pair, 16 KB
  __shared__ float red[2][4][64];    // 2 KB

  const int ray = blockIdx.x;        // ray = ti*NP + pj
  const int ti = ray >> 5;
  const int pj = ray & 31;
  const float th = (float)ti * (float)(M_PI / 2.0 / (NT - 1));
  const float ph = (float)(-M_PI / 2.0) + (float)pj * (float)(M_PI / (NP - 1));
  float sth, cth, sph, cph;
  sincosf(th, &sth, &cth);
  sincosf(ph, &sph, &cph);
  const float dx = sth * cph, dy = sth * sph, dz = cth;
  const float dxx = dx*dx, dyy = dy*dy, dzz = dz*dz;
  const float dxy = 2.f*dx*dy, dxz = 2.f*dx*dz, dyz = 2.f*dy*dz;

  const int tid = threadIdx.x;
  const float cx = cam[0], cy = cam[1], cz = cam[2];

  // Phase 0: 4 pairs (8 gaussians) per thread
  #pragma unroll
  for (int i = 0; i < 4; ++i) {
    int p = tid + i * 256;
    float4 r0 = gauss_coef(2*p,   means, scales, rots, opacs, feats,
                           cx, cy, cz, dxx, dyy, dzz, dxy, dxz, dyz, dx, dy, dz);
    float4 r1 = gauss_coef(2*p+1, means, scales, rots, opacs, feats,
                           cx, cy, cz, dxx, dyy, dzz, dxy, dxz, dyz, dx, dy, dz);
    ab[p] = make_float4(r0.x, r1.x, r0.y, r1.y);
    ca[p] = make_float4(r0.z, r1.z, r0.w, r1.w);
  }
  __syncthreads();

  // Phase 1: each wave handles 256 pairs; lane = t sample.
  const int lane = tid & 63;
  const int wv = tid >> 6;
  const float t = 0.5f + (float)lane * (2.0f / 63.0f);
  const f32x2 tt = {t, t};
  const f32x2 one = {1.f, 1.f};

  const float4* pab = ab + wv * (NPAIR / 4);
  const float4* pca = ca + wv * (NPAIR / 4);
  f32x2 dA = {0.f, 0.f}, dB = {0.f, 0.f};
  f32x2 hA = {0.f, 0.f}, hB = {0.f, 0.f};
  #pragma unroll 4
  for (int j = 0; j < NPAIR / 4; j += 2) {
    float4 u0 = pab[j],     v0 = pca[j];
    float4 u1 = pab[j + 1], v1 = pca[j + 1];
    f32x2 A0 = {u0.x, u0.y}, B0 = {u0.z, u0.w}, C0 = {v0.x, v0.y}, L0 = {v0.z, v0.w};
    f32x2 A1 = {u1.x, u1.y}, B1 = {u1.z, u1.w}, C1 = {v1.x, v1.y}, L1 = {v1.z, v1.w};
    f32x2 q0 = pk_fma(pk_fma(A0, tt, B0), tt, C0);
    f32x2 q1 = pk_fma(pk_fma(A1, tt, B1), tt, C1);
    f32x2 x0, x1;
    x0.x = __builtin_amdgcn_exp2f(q0.x); x0.y = __builtin_amdgcn_exp2f(q0.y);
    x1.x = __builtin_amdgcn_exp2f(q1.x); x1.y = __builtin_amdgcn_exp2f(q1.y);
    dA = pk_fma(x0, one, dA); hA = pk_fma(x0, L0, hA);
    dB = pk_fma(x1, one, dB); hB = pk_fma(x1, L1, hB);
  }
  red[0][wv][lane] = (dA.x + dA.y) + (dB.x + dB.y);
  red[1][wv][lane] = (hA.x + hA.y) + (hB.x + hB.y);
  __syncthreads();

  // Phase 2: reduce across 4 waves, then transmittance scan over t (wave 0).
  if (tid < 64) {
    float D  = (red[0][0][tid] + red[0][1][tid]) + (red[0][2][tid] + red[0][3][tid]);
    float Rh = (red[1][0][tid] + red[1][1][tid]) + (red[1][2][tid] + red[1][3][tid]);
    const float step = 1.0f * 0.03125f;  // C_LIGHT * DELTA_T
    float s = D * step;
    float inc = s;
    #pragma unroll
    for (int off = 1; off < 64; off <<= 1) {
      float v = __shfl_up(inc, off, 64);
      if (tid >= off) inc += v;
    }
    float excl = inc - s;
    float T = __builtin_amdgcn_exp2f(-1.4426950408889634f * excl);
    float tt2 = 0.5f + (float)tid * (2.0f / 63.0f);
    float res = Rh * T / (tt2 * tt2 + 1e-8f) * sth;
    out[tid * NRAY + ray] = res;
  }
}

// ---------------------------------------------------------------------------
// Histogram. One block per t bin; sum 1024 rays.
// ---------------------------------------------------------------------------
__global__ __launch_bounds__(256) void k_hist(const float* __restrict__ res,
                                              float* __restrict__ hist) {
  const int t = blockIdx.x;
  const int tid = threadIdx.x;
  float s = 0.f;
  #pragma unroll
  for (int r = tid; r < NRAY; r += 256) s += res[t * NRAY + r];
  #pragma unroll
  for (int off = 32; off > 0; off >>= 1) s += __shfl_down(s, off, 64);
  __shared__ float sm[4];
  if ((tid & 63) == 0) sm[tid >> 6] = s;
  __syncthreads();
  if (tid == 0) {
    const float dtdp = (float)((M_PI / 2.0 / NT) * (M_PI / NP));
    hist[t] = ((sm[0] + sm[1]) + (sm[2] + sm[3])) * dtdp;
  }
}

extern "C" void kernel_launch(void* const* d_in, const int* in_sizes, int n_in,
                              void* d_out, int out_size, void* d_ws, size_t ws_size,
                              hipStream_t stream) {
  const float* means  = (const float*)d_in[0];
  const float* scales = (const float*)d_in[1];
  const float* rots   = (const float*)d_in[2];
  const float* opacs  = (const float*)d_in[3];
  const float* feats  = (const float*)d_in[4];
  const float* cam    = (const float*)d_in[5];
  // d_in[6..8] = num_theta/num_phi/num_r (fixed at 32/32/64 per setup_inputs)

  float* out = (float*)d_out;

  k_main<<<NRAY, 256, 0, stream>>>(means, scales, rots, opacs, feats, cam, out);
  k_hist<<<NR,   256, 0, stream>>>(out, out + NR * NRAY);
}